// Round 1
// baseline (821.410 us; speedup 1.0000x reference)
//
#include <hip/hip_runtime.h>
#include <hip/hip_bf16.h>

typedef __attribute__((ext_vector_type(8))) short short8;
typedef __attribute__((ext_vector_type(4))) float f32x4;

#define NTOP 1000
#define NPAD 1024
#define KC   256
#define MROWS 40000

static __device__ __forceinline__ unsigned short f2bf(float x) {
    union { float f; unsigned u; } v; v.f = x;
    unsigned r = (v.u + 0x7FFFu + ((v.u >> 16) & 1u)) >> 16;
    return (unsigned short)r;
}

// Kernel 1: colsum[j] = sum_i nw[i,j]; also zero the output accumulator.
__global__ void k_prep(const float* __restrict__ nw,
                       float* __restrict__ colsum,
                       float* __restrict__ out) {
    int j = blockIdx.x * 256 + threadIdx.x;
    if (j == 0) out[0] = 0.f;
    if (j < NTOP) {
        float s = 0.f;
        for (int i = 0; i < NTOP; ++i) s += nw[(size_t)i * NTOP + j];
        colsum[j] = s;
    }
}

// Kernel 2: Bpad[j,k] = bf16(V[j,k]*colsum[j] + 0.1*noise[j,k]), zero-padded to NPAD rows.
__global__ void k_vj(const float* __restrict__ V,
                     const float* __restrict__ noise,
                     const float* __restrict__ colsum,
                     unsigned short* __restrict__ Bpad) {
    int idx = blockIdx.x * 256 + threadIdx.x;   // over NPAD*KC
    int j = idx >> 8;
    float x = 0.f;
    if (j < NTOP) x = V[idx] * colsum[j] + 0.1f * noise[idx];
    Bpad[idx] = f2bf(x);
}

// Kernel 3: fused U_emb + GEMM(A@B^T) + sigmoid + masked Normal log-prob + reduce.
// One wave (64 threads) per 16 rows of M. A-frags built from U once, held in regs.
__global__ __launch_bounds__(64) void k_main(
    const float* __restrict__ U, const float* __restrict__ w5,
    const float* __restrict__ b1, const unsigned short* __restrict__ Bpad,
    const float* __restrict__ R, const int* __restrict__ C,
    float* __restrict__ out)
{
    const int l  = threadIdx.x;
    const int lm = l & 15;       // A row within tile / B row (n) within tile
    const int lq = l >> 4;       // quad: k-offset selector
    const int m0 = blockIdx.x << 4;

    const float w0 = w5[0], w1 = w5[1], w2 = w5[2], w3 = w5[3], w4 = w5[4];
    const float bb = b1[0];

    // ---- Build 8 A-fragments: U_emb[m0+lm, k] in bf16, k = s*32 + lq*8 + j ----
    short8 afr[8];
    {
        const int m = m0 + lm;
        #pragma unroll
        for (int s = 0; s < 8; ++s) {
            const float4* up4 = reinterpret_cast<const float4*>(
                U + (size_t)(m * KC + s * 32 + lq * 8) * 5);
            float u[40];
            #pragma unroll
            for (int i = 0; i < 10; ++i) {
                float4 t = up4[i];
                u[i*4+0] = t.x; u[i*4+1] = t.y; u[i*4+2] = t.z; u[i*4+3] = t.w;
            }
            union { short8 v; unsigned short us[8]; } pk;
            #pragma unroll
            for (int j = 0; j < 8; ++j) {
                float e = u[j*5+0]*w0 + u[j*5+1]*w1 + u[j*5+2]*w2
                        + u[j*5+3]*w3 + u[j*5+4]*w4 + bb;
                pk.us[j] = f2bf(e);
            }
            afr[s] = pk.v;
        }
    }

    const int kb = lq * 8;
    float lpsum = 0.f;

    for (int ns = 0; ns < NPAD / 64; ++ns) {
        const int n0 = ns << 6;
        f32x4 acc[4];
        #pragma unroll
        for (int t = 0; t < 4; ++t) acc[t] = (f32x4){0.f, 0.f, 0.f, 0.f};

        #pragma unroll
        for (int s = 0; s < 8; ++s) {
            #pragma unroll
            for (int t = 0; t < 4; ++t) {
                const short8 bfr = *reinterpret_cast<const short8*>(
                    Bpad + (size_t)(n0 + t * 16 + lm) * KC + s * 32 + kb);
                acc[t] = __builtin_amdgcn_mfma_f32_16x16x32_bf16(afr[s], bfr, acc[t], 0, 0, 0);
            }
        }

        // Epilogue: C/D layout n = lane&15, m = (lane>>4)*4 + reg
        #pragma unroll
        for (int t = 0; t < 4; ++t) {
            const int n = n0 + t * 16 + lm;
            if (n < NTOP) {
                const size_t base = (size_t)(m0 + lq * 4) * NTOP + n;
                #pragma unroll
                for (int r = 0; r < 4; ++r) {
                    float x   = acc[t][r];
                    float muv = 1.f / (1.f + __expf(-x));
                    float d   = R[base + (size_t)r * NTOP] - muv;
                    float lp  = -50.f * d * d + 1.3836465597893728f;
                    if (C[base + (size_t)r * NTOP] == 1) lpsum += lp;
                }
            }
        }
    }

    #pragma unroll
    for (int off = 32; off > 0; off >>= 1) lpsum += __shfl_down(lpsum, off);
    if (l == 0) atomicAdd(out, lpsum);
}

extern "C" void kernel_launch(void* const* d_in, const int* in_sizes, int n_in,
                              void* d_out, int out_size, void* d_ws, size_t ws_size,
                              hipStream_t stream) {
    const float* V     = (const float*)d_in[1];
    const float* R     = (const float*)d_in[2];
    const float* nw    = (const float*)d_in[3];
    const float* U     = (const float*)d_in[4];
    const float* w5    = (const float*)d_in[5];
    const float* b1    = (const float*)d_in[6];
    const float* noise = (const float*)d_in[7];
    const int*   C     = (const int*)d_in[8];
    float* out = (float*)d_out;

    float* colsum        = (float*)d_ws;
    unsigned short* Bpad = (unsigned short*)((char*)d_ws + 8192);

    hipLaunchKernelGGL(k_prep, dim3(4), dim3(256), 0, stream, nw, colsum, out);
    hipLaunchKernelGGL(k_vj, dim3(NPAD * KC / 256), dim3(256), 0, stream,
                       V, noise, colsum, Bpad);
    hipLaunchKernelGGL(k_main, dim3(MROWS / 16), dim3(64), 0, stream,
                       U, w5, b1, Bpad, R, C, out);
}